// Round 4
// baseline (319.971 us; speedup 1.0000x reference)
//
#include <hip/hip_runtime.h>
#include <hip/hip_bf16.h>
#include <hip/hip_cooperative_groups.h>
#include <math.h>

namespace cg = cooperative_groups;

#define BATCH 1024
#define NBLK 256
#define BM 64
#define BN 64
#define BK 32
#define LDK 40   // padded LDS row stride (bf16): 80 B rows -> 16B-aligned frags, ~2-way conflicts max

typedef __attribute__((ext_vector_type(8))) short bf16x8;
typedef __attribute__((ext_vector_type(4))) float f32x4;

static __device__ __forceinline__ ushort f2bf(float f) {
    union { float f; unsigned u; } v; v.f = f;
    unsigned r = (v.u + 0x7fffu + ((v.u >> 16) & 1u)) >> 16;  // RNE
    return (ushort)r;
}

// ---------------- bf16-MFMA GEMM phase (tile-stride) with fused euclid norms ----------------
// Z[b,j] = (x@w)[b,j] - 0.5*(xsq[b]+wsq[j]); dot in bf16 MFMA (fp32 accum), norms fp32.
static __device__ void gemm_mfma_phase(
    const float* __restrict__ A, const float* __restrict__ Bw, float* __restrict__ Z,
    int M, int K, int N,
    ushort (*As)[BM][LDK], ushort (*Bs)[BN][LDK], float* fbuf, int bid, int tid)
{
    float* bred  = fbuf;         // [4][BN]
    float* xsq_s = fbuf + 256;   // [BM]
    float* wsq_s = fbuf + 320;   // [BN]

    const int lane = tid & 63;
    const int wv = tid >> 6;
    const int wr = wv >> 1, wc = wv & 1;      // 2x2 waves, 32x32 out each
    const int ar = tid >> 3;                  // 0..31
    const int ak = (tid & 7) * 4;             // 0..28
    const int bn = tid & 63;
    const int bk = tid >> 6;                  // 0..3
    const int fr = lane & 15;
    const int fg = lane >> 4;

    const int ntm = M / BM;
    const int ntn = (N + BN - 1) / BN;
    const int ntiles = (K + BK - 1) / BK;

    for (int tile = bid; tile < ntm * ntn; tile += NBLK) {
        const int row0 = (tile % ntm) * BM;
        const int col0 = (tile / ntm) * BN;

        f32x4 acc[2][2] = {};
        float asq[2] = {0.f, 0.f};
        float bsq = 0.f;
        float areg[2][4];
        float breg[8];

        auto load_tile = [&](int t) {
            const int kbase = t * BK;
            if (kbase + BK <= K) {
                #pragma unroll
                for (int l = 0; l < 2; ++l) {
                    const float* p = A + (size_t)(row0 + ar + 32 * l) * K + kbase + ak;
                    f32x4 v = *(const f32x4*)p;
                    #pragma unroll
                    for (int j = 0; j < 4; ++j) areg[l][j] = v[j];
                }
                const int gc = col0 + bn;
                #pragma unroll
                for (int i = 0; i < 8; ++i)
                    breg[i] = (gc < N) ? Bw[(size_t)(kbase + bk + 4 * i) * N + gc] : 0.f;
            } else {
                #pragma unroll
                for (int l = 0; l < 2; ++l)
                    #pragma unroll
                    for (int j = 0; j < 4; ++j) {
                        int gk = kbase + ak + j;
                        areg[l][j] = (gk < K) ? A[(size_t)(row0 + ar + 32 * l) * K + gk] : 0.f;
                    }
                const int gc = col0 + bn;
                #pragma unroll
                for (int i = 0; i < 8; ++i) {
                    int gk = kbase + bk + 4 * i;
                    breg[i] = (gk < K && gc < N) ? Bw[(size_t)gk * N + gc] : 0.f;
                }
            }
        };

        auto store_tile = [&](int buf) {
            #pragma unroll
            for (int l = 0; l < 2; ++l) {
                ushort4 h;
                h.x = f2bf(areg[l][0]); h.y = f2bf(areg[l][1]);
                h.z = f2bf(areg[l][2]); h.w = f2bf(areg[l][3]);
                asq[l] += areg[l][0]*areg[l][0] + areg[l][1]*areg[l][1]
                        + areg[l][2]*areg[l][2] + areg[l][3]*areg[l][3];
                *(ushort4*)&As[buf][ar + 32 * l][ak] = h;
            }
            #pragma unroll
            for (int i = 0; i < 8; ++i) {
                bsq += breg[i] * breg[i];
                Bs[buf][bn][bk + 4 * i] = f2bf(breg[i]);
            }
        };

        auto compute = [&](int buf) {
            bf16x8 af[2], bfr[2];
            #pragma unroll
            for (int m = 0; m < 2; ++m)
                af[m] = *(const bf16x8*)&As[buf][wr * 32 + m * 16 + fr][fg * 8];
            #pragma unroll
            for (int n = 0; n < 2; ++n)
                bfr[n] = *(const bf16x8*)&Bs[buf][wc * 32 + n * 16 + fr][fg * 8];
            #pragma unroll
            for (int m = 0; m < 2; ++m)
                #pragma unroll
                for (int n = 0; n < 2; ++n)
                    acc[m][n] = __builtin_amdgcn_mfma_f32_16x16x32_bf16(af[m], bfr[n], acc[m][n], 0, 0, 0);
        };

        load_tile(0);
        store_tile(0);
        __syncthreads();
        for (int t = 0; t < ntiles; ++t) {
            if (t + 1 < ntiles) load_tile(t + 1);
            compute(t & 1);
            if (t + 1 < ntiles) store_tile((t + 1) & 1);
            __syncthreads();
        }

        // xsq: reduce over 8 threads sharing a row
        #pragma unroll
        for (int l = 0; l < 2; ++l) {
            float s = asq[l];
            s += __shfl_xor(s, 1, 64);
            s += __shfl_xor(s, 2, 64);
            s += __shfl_xor(s, 4, 64);
            if ((tid & 7) == 0) xsq_s[ar + 32 * l] = s;
        }
        // wsq: fold 4 k-slices
        bred[bk * BN + bn] = bsq;
        __syncthreads();
        if (tid < BN) wsq_s[tid] = bred[0*BN+tid] + bred[1*BN+tid] + bred[2*BN+tid] + bred[3*BN+tid];
        __syncthreads();

        // epilogue: C/D layout col=lane&15, row=(lane>>4)*4+reg
        #pragma unroll
        for (int n = 0; n < 2; ++n) {
            int c = col0 + wc * 32 + n * 16 + fr;
            if (c >= N) continue;
            float wsq = wsq_s[wc * 32 + n * 16 + fr];
            #pragma unroll
            for (int m = 0; m < 2; ++m) {
                #pragma unroll
                for (int j = 0; j < 4; ++j) {
                    int rl = wr * 32 + m * 16 + fg * 4 + j;
                    int r = row0 + rl;
                    if (r < M) Z[(size_t)r * N + c] = acc[m][n][j] - 0.5f * (xsq_s[rl] + wsq);
                }
            }
        }
        __syncthreads();
    }
}

// ---------------- BatchNorm(train)+act phase (column-stride) ----------------
template <int ACT>
static __device__ void bn_phase(const float* __restrict__ zz, const float* __restrict__ gamma,
                                const float* __restrict__ beta, float* __restrict__ h,
                                int N, int bid, int tid, float* fbuf)
{
    for (int j = bid; j < N; j += NBLK) {
        float v[4];
        #pragma unroll
        for (int k = 0; k < 4; ++k) v[k] = zz[(size_t)(tid + k * 256) * N + j];

        float s = v[0] + v[1] + v[2] + v[3];
        #pragma unroll
        for (int off = 32; off; off >>= 1) s += __shfl_down(s, off, 64);
        int lane = tid & 63, wid = tid >> 6;
        if (lane == 0) fbuf[wid] = s;
        __syncthreads();
        float mean = (fbuf[0] + fbuf[1] + fbuf[2] + fbuf[3]) * (1.f / BATCH);
        __syncthreads();

        float ss = 0.f;
        #pragma unroll
        for (int k = 0; k < 4; ++k) { float d = v[k] - mean; ss += d * d; }
        #pragma unroll
        for (int off = 32; off; off >>= 1) ss += __shfl_down(ss, off, 64);
        if (lane == 0) fbuf[wid] = ss;
        __syncthreads();
        float var = (fbuf[0] + fbuf[1] + fbuf[2] + fbuf[3]) * (1.f / BATCH);

        float inv = 1.f / sqrtf(var + 1e-5f);
        float g = gamma[j], bb = beta[j];
        #pragma unroll
        for (int k = 0; k < 4; ++k) {
            float y = g * (v[k] - mean) * inv + bb;
            if (ACT == 0) y = y > 0.f ? y : 0.f;
            else          y = 1.f / (1.f + expf(-y));
            h[(size_t)(tid + k * 256) * N + j] = y;
        }
        __syncthreads();
    }
}

// ---------------- layer-2 GEMM: h1[1024,392] @ W2[392,8], fp32, norms inline ----------------
static __device__ void gemm2_phase(const float* __restrict__ h1, const float* __restrict__ W2,
                                   float* __restrict__ zz, int bid, int tid, float* fbuf)
{
    if (bid >= 32) return;
    for (int i = tid; i < 392 * 8; i += 256) fbuf[i] = W2[i];
    __syncthreads();
    const int c = tid & 7;
    const int r = bid * 32 + (tid >> 3);
    const float* hr = h1 + (size_t)r * 392;
    float acc = 0.f, sh = 0.f, sw = 0.f;
    #pragma unroll 8
    for (int k = 0; k < 392; ++k) {
        float hv = hr[k], wv = fbuf[k * 8 + c];
        acc += hv * wv; sh += hv * hv; sw += wv * wv;
    }
    zz[(size_t)r * 8 + c] = acc - 0.5f * (sh + sw);
}

// ---------------- layer-3 GEMM: h2[1024,8] @ W3[8,392], fp32, norms inline ----------------
static __device__ void gemm3_phase(const float* __restrict__ h2, const float* __restrict__ W3,
                                   float* __restrict__ zz, int bid, int tid, float* fbuf)
{
    for (int i = tid; i < 8 * 392; i += 256) fbuf[i] = W3[i];
    __syncthreads();
    const int r = bid * 4 + (tid >> 6);
    const float* hr = h2 + (size_t)r * 8;
    float hv[8], sh = 0.f;
    #pragma unroll
    for (int k = 0; k < 8; ++k) { hv[k] = hr[k]; sh += hv[k] * hv[k]; }
    for (int c0 = 0; c0 < 392; c0 += 64) {
        int c = c0 + (tid & 63);
        if (c < 392) {
            float acc = 0.f, sw = 0.f;
            #pragma unroll
            for (int k = 0; k < 8; ++k) {
                float wv = fbuf[k * 392 + c];
                acc += hv[k] * wv; sw += wv * wv;
            }
            zz[(size_t)r * 392 + c] = acc - 0.5f * (sh + sw);
        }
    }
}

// ---------------- the whole network in one cooperative launch ----------------
__global__ __launch_bounds__(256) void meganet(
    const float* X,
    const float* W1, const float* g1, const float* b1,
    const float* W2, const float* g2, const float* b2,
    const float* W3, const float* g3, const float* b3,
    const float* W4, const float* g4, const float* b4,
    float* z, float* h1, float* h2, float* h3, float* outp)
{
    cg::grid_group grid = cg::this_grid();
    __shared__ ushort As[2][BM][LDK];
    __shared__ ushort Bs[2][BN][LDK];
    __shared__ float fbuf[3200];
    const int tid = threadIdx.x;
    const int bid = blockIdx.x;

    gemm_mfma_phase(X, W1, z, BATCH, 784, 392, As, Bs, fbuf, bid, tid);
    grid.sync();
    bn_phase<0>(z, g1, b1, h1, 392, bid, tid, fbuf);
    grid.sync();
    gemm2_phase(h1, W2, z, bid, tid, fbuf);
    grid.sync();
    bn_phase<0>(z, g2, b2, h2, 8, bid, tid, fbuf);
    grid.sync();
    gemm3_phase(h2, W3, z, bid, tid, fbuf);
    grid.sync();
    bn_phase<0>(z, g3, b3, h3, 392, bid, tid, fbuf);
    grid.sync();
    gemm_mfma_phase(h3, W4, z, BATCH, 392, 784, As, Bs, fbuf, bid, tid);
    grid.sync();
    bn_phase<1>(z, g4, b4, outp, 784, bid, tid, fbuf);
}

extern "C" void kernel_launch(void* const* d_in, const int* in_sizes, int n_in,
                              void* d_out, int out_size, void* d_ws, size_t ws_size,
                              hipStream_t stream) {
    const float* X  = (const float*)d_in[0];
    const float* W1 = (const float*)d_in[1];
    const float* g1 = (const float*)d_in[2];
    const float* b1 = (const float*)d_in[3];
    const float* W2 = (const float*)d_in[4];
    const float* g2 = (const float*)d_in[5];
    const float* b2 = (const float*)d_in[6];
    const float* W3 = (const float*)d_in[7];
    const float* g3 = (const float*)d_in[8];
    const float* b3 = (const float*)d_in[9];
    const float* W4 = (const float*)d_in[10];
    const float* g4 = (const float*)d_in[11];
    const float* b4 = (const float*)d_in[12];

    float* ws  = (float*)d_ws;
    float* z   = ws;                  // 1024*784
    float* h1  = z   + 1024 * 784;    // 1024*392
    float* h2  = h1  + 1024 * 392;    // 1024*8
    float* h3  = h2  + 1024 * 8;      // 1024*392
    float* outp = (float*)d_out;

    void* args[] = {
        (void*)&X,
        (void*)&W1, (void*)&g1, (void*)&b1,
        (void*)&W2, (void*)&g2, (void*)&b2,
        (void*)&W3, (void*)&g3, (void*)&b3,
        (void*)&W4, (void*)&g4, (void*)&b4,
        (void*)&z, (void*)&h1, (void*)&h2, (void*)&h3, (void*)&outp,
    };
    hipLaunchCooperativeKernel((void*)meganet, dim3(NBLK), dim3(256), args, 0, stream);
}

// Round 5
// 88.732 us; speedup vs baseline: 3.6060x; 3.6060x over previous
//
#include <hip/hip_runtime.h>
#include <hip/hip_bf16.h>
#include <math.h>

#define BATCH 1024
#define BM 64
#define BN 64
#define BK 32
#define LDK 40   // padded LDS row stride (bf16): 80 B rows -> 16B-aligned frags, ~2-way conflicts max

typedef __attribute__((ext_vector_type(8))) short bf16x8;
typedef __attribute__((ext_vector_type(4))) float f32x4;

static __device__ __forceinline__ ushort f2bf(float f) {
    union { float f; unsigned u; } v; v.f = f;
    unsigned r = (v.u + 0x7fffu + ((v.u >> 16) & 1u)) >> 16;  // RNE
    return (ushort)r;
}

// ============ fused GEMM: [optional consumer-side BN+ReLU on A] + euclid + column-stat partials ============
// A_eff[r][k] = NORM ? relu(A[r][k]*scale_k + shift_k) : A[r][k]
//   (scale/shift finalized in-block from producer's per-rowblock (sum,sumsq) float2 partials)
// Z[r][c] = A_eff[r]·B[:,c] - 0.5*(||A_eff[r]||^2 + ||B[:,c]||^2)     (dot in bf16 MFMA, rest fp32)
// stats_out[rowblock][c] = (sum_r z, sum_r z^2) over this block's 64 rows — feeds the next layer's BN.
template <int NORM>
__global__ __launch_bounds__(256) void gemm_fused(
    const float* __restrict__ A, const float* __restrict__ Bw,
    const float2* __restrict__ stats_in, const float* __restrict__ gamma, const float* __restrict__ beta,
    float* __restrict__ Z, float2* __restrict__ stats_out,
    int M, int K, int N)
{
    __shared__ ushort As[2][BM][LDK];
    __shared__ ushort Bs[2][BN][LDK];
    __shared__ float scaleK[784], shiftK[784];
    __shared__ float bred[4 * BN];
    __shared__ float xsq_s[BM], wsq_s[BN];
    __shared__ float cs[2][BN], cq[2][BN];

    const int tid = threadIdx.x;
    const int lane = tid & 63;
    const int wv = tid >> 6;
    const int wr = wv >> 1, wc = wv & 1;      // 2x2 waves, 32x32 out each
    const int row0 = blockIdx.y * BM, col0 = blockIdx.x * BN;
    const int ar = tid >> 3;                  // 0..31
    const int ak = (tid & 7) * 4;             // 0..28
    const int bn = tid & 63;
    const int bk = tid >> 6;                  // 0..3
    const int fr = lane & 15;
    const int fg = lane >> 4;

    // ---- finalize BN stats for the K (input-feature) columns ----
    if (NORM) {
        for (int k = tid; k < K; k += 256) {
            double s = 0.0, q = 0.0;
            #pragma unroll 4
            for (int rb = 0; rb < 16; ++rb) {
                float2 p = stats_in[rb * K + k];
                s += (double)p.x; q += (double)p.y;
            }
            double mean = s * (1.0 / BATCH);
            double var = q * (1.0 / BATCH) - mean * mean;
            float inv = (float)(1.0 / sqrt(var + 1e-5));
            float sc = gamma[k] * inv;
            scaleK[k] = sc;
            shiftK[k] = beta[k] - (float)mean * sc;
        }
        __syncthreads();
    }

    f32x4 acc[2][2] = {};
    float asq[2] = {0.f, 0.f};
    float bsq = 0.f;
    float areg[2][4];
    float breg[8];
    const int ntiles = (K + BK - 1) / BK;

    auto load_tile = [&](int t) {
        const int kbase = t * BK;
        if (kbase + BK <= K) {
            #pragma unroll
            for (int l = 0; l < 2; ++l) {
                const float* p = A + (size_t)(row0 + ar + 32 * l) * K + kbase + ak;
                f32x4 v = *(const f32x4*)p;
                #pragma unroll
                for (int j = 0; j < 4; ++j) {
                    float x = v[j];
                    if (NORM) x = fmaxf(x * scaleK[kbase + ak + j] + shiftK[kbase + ak + j], 0.f);
                    areg[l][j] = x;
                }
            }
            const int gc = col0 + bn;
            #pragma unroll
            for (int i = 0; i < 8; ++i)
                breg[i] = (gc < N) ? Bw[(size_t)(kbase + bk + 4 * i) * N + gc] : 0.f;
        } else {
            #pragma unroll
            for (int l = 0; l < 2; ++l)
                #pragma unroll
                for (int j = 0; j < 4; ++j) {
                    int gk = kbase + ak + j;
                    float x = 0.f;
                    if (gk < K) {
                        x = A[(size_t)(row0 + ar + 32 * l) * K + gk];
                        if (NORM) x = fmaxf(x * scaleK[gk] + shiftK[gk], 0.f);
                    }
                    areg[l][j] = x;
                }
            const int gc = col0 + bn;
            #pragma unroll
            for (int i = 0; i < 8; ++i) {
                int gk = kbase + bk + 4 * i;
                breg[i] = (gk < K && gc < N) ? Bw[(size_t)gk * N + gc] : 0.f;
            }
        }
    };

    auto store_tile = [&](int buf) {
        #pragma unroll
        for (int l = 0; l < 2; ++l) {
            ushort4 h;
            h.x = f2bf(areg[l][0]); h.y = f2bf(areg[l][1]);
            h.z = f2bf(areg[l][2]); h.w = f2bf(areg[l][3]);
            asq[l] += areg[l][0]*areg[l][0] + areg[l][1]*areg[l][1]
                    + areg[l][2]*areg[l][2] + areg[l][3]*areg[l][3];
            *(ushort4*)&As[buf][ar + 32 * l][ak] = h;
        }
        #pragma unroll
        for (int i = 0; i < 8; ++i) {
            bsq += breg[i] * breg[i];
            Bs[buf][bn][bk + 4 * i] = f2bf(breg[i]);
        }
    };

    auto compute = [&](int buf) {
        bf16x8 af[2], bfr[2];
        #pragma unroll
        for (int m = 0; m < 2; ++m)
            af[m] = *(const bf16x8*)&As[buf][wr * 32 + m * 16 + fr][fg * 8];
        #pragma unroll
        for (int n = 0; n < 2; ++n)
            bfr[n] = *(const bf16x8*)&Bs[buf][wc * 32 + n * 16 + fr][fg * 8];
        #pragma unroll
        for (int m = 0; m < 2; ++m)
            #pragma unroll
            for (int n = 0; n < 2; ++n)
                acc[m][n] = __builtin_amdgcn_mfma_f32_16x16x32_bf16(af[m], bfr[n], acc[m][n], 0, 0, 0);
    };

    load_tile(0);
    store_tile(0);
    __syncthreads();
    for (int t = 0; t < ntiles; ++t) {
        if (t + 1 < ntiles) load_tile(t + 1);
        compute(t & 1);
        if (t + 1 < ntiles) store_tile((t + 1) & 1);
        __syncthreads();
    }

    // ---- xsq: reduce over 8 threads sharing a row ----
    #pragma unroll
    for (int l = 0; l < 2; ++l) {
        float s = asq[l];
        s += __shfl_xor(s, 1, 64);
        s += __shfl_xor(s, 2, 64);
        s += __shfl_xor(s, 4, 64);
        if ((tid & 7) == 0) xsq_s[ar + 32 * l] = s;
    }
    // ---- wsq: fold 4 k-slices ----
    bred[bk * BN + bn] = bsq;
    __syncthreads();
    if (tid < BN) wsq_s[tid] = bred[0*BN+tid] + bred[1*BN+tid] + bred[2*BN+tid] + bred[3*BN+tid];
    __syncthreads();

    // ---- epilogue: fold euclid adjust into acc, write Z, accumulate column stats ----
    // C/D layout: col = lane&15 (fr), row = fg*4 + reg
    #pragma unroll
    for (int n = 0; n < 2; ++n) {
        const int c64 = wc * 32 + n * 16 + fr;
        const int c = col0 + c64;
        const float wsq = wsq_s[c64];
        float ps = 0.f, pq = 0.f;
        #pragma unroll
        for (int m = 0; m < 2; ++m) {
            #pragma unroll
            for (int j = 0; j < 4; ++j) {
                const int rl = wr * 32 + m * 16 + fg * 4 + j;
                float zv = acc[m][n][j] - 0.5f * (xsq_s[rl] + wsq);
                ps += zv; pq += zv * zv;
                if (c < N) Z[(size_t)(row0 + rl) * N + c] = zv;
            }
        }
        // fold the 4 fg-groups (rows) for this wave's 32-row half
        ps += __shfl_xor(ps, 16, 64); ps += __shfl_xor(ps, 32, 64);
        pq += __shfl_xor(pq, 16, 64); pq += __shfl_xor(pq, 32, 64);
        if (fg == 0) { cs[wr][c64] = ps; cq[wr][c64] = pq; }
    }
    __syncthreads();
    if (tid < BN) {
        int c = col0 + tid;
        if (c < N)
            stats_out[blockIdx.y * N + c] = make_float2(cs[0][tid] + cs[1][tid],
                                                        cq[0][tid] + cq[1][tid]);
    }
}

// ============ final BN + sigmoid, in place on d_out ============
__global__ __launch_bounds__(256) void bn_sigmoid_inplace(
    float* __restrict__ Zout, const float2* __restrict__ stats,
    const float* __restrict__ gamma, const float* __restrict__ beta, int N)
{
    __shared__ float sc[784], sh[784];
    for (int k = threadIdx.x; k < N; k += 256) {
        double s = 0.0, q = 0.0;
        #pragma unroll 4
        for (int rb = 0; rb < 16; ++rb) {
            float2 p = stats[rb * N + k];
            s += (double)p.x; q += (double)p.y;
        }
        double mean = s * (1.0 / BATCH);
        double var = q * (1.0 / BATCH) - mean * mean;
        float inv = (float)(1.0 / sqrt(var + 1e-5));
        float scv = gamma[k] * inv;
        sc[k] = scv;
        sh[k] = beta[k] - (float)mean * scv;
    }
    __syncthreads();
    const int nf4 = BATCH * N / 4;
    f32x4* p = (f32x4*)Zout;
    for (int i = blockIdx.x * 256 + threadIdx.x; i < nf4; i += gridDim.x * 256) {
        f32x4 v = p[i];
        int k = (i * 4) % N;
        #pragma unroll
        for (int j = 0; j < 4; ++j) {
            float y = v[j] * sc[k + j] + sh[k + j];
            v[j] = 1.f / (1.f + expf(-y));
        }
        p[i] = v;
    }
}

extern "C" void kernel_launch(void* const* d_in, const int* in_sizes, int n_in,
                              void* d_out, int out_size, void* d_ws, size_t ws_size,
                              hipStream_t stream) {
    const float* X  = (const float*)d_in[0];
    const float* W1 = (const float*)d_in[1];
    const float* g1 = (const float*)d_in[2];
    const float* b1 = (const float*)d_in[3];
    const float* W2 = (const float*)d_in[4];
    const float* g2 = (const float*)d_in[5];
    const float* b2 = (const float*)d_in[6];
    const float* W3 = (const float*)d_in[7];
    const float* g3 = (const float*)d_in[8];
    const float* b3 = (const float*)d_in[9];
    const float* W4 = (const float*)d_in[10];
    const float* g4 = (const float*)d_in[11];
    const float* b4 = (const float*)d_in[12];

    float* ws = (float*)d_ws;
    float*  z1  = ws;                       // 1024*392
    float*  z2  = z1 + 1024 * 392;          // 1024*8
    float*  z3  = z2 + 1024 * 8;            // 1024*392
    float2* st1 = (float2*)(z3 + 1024 * 392);       // [16][392]
    float2* st2 = st1 + 16 * 392;                   // [16][8]
    float2* st3 = st2 + 16 * 8;                     // [16][392]
    float2* st4 = st3 + 16 * 392;                   // [16][784]
    float* outp = (float*)d_out;

    // L1: X[1024,784] -> z1[1024,392]           (A raw)
    gemm_fused<0><<<dim3(7, 16), 256, 0, stream>>>(X, W1, nullptr, nullptr, nullptr,
                                                   z1, st1, BATCH, 784, 392);
    // L2: relu(bn(z1)) @ W2 -> z2[1024,8]
    gemm_fused<1><<<dim3(1, 16), 256, 0, stream>>>(z1, W2, st1, g1, b1,
                                                   z2, st2, BATCH, 392, 8);
    // L3: relu(bn(z2)) @ W3 -> z3[1024,392]
    gemm_fused<1><<<dim3(7, 16), 256, 0, stream>>>(z2, W3, st2, g2, b2,
                                                   z3, st3, BATCH, 8, 392);
    // L4: relu(bn(z3)) @ W4 -> d_out (pre-BN z4)
    gemm_fused<1><<<dim3(13, 16), 256, 0, stream>>>(z3, W4, st3, g3, b3,
                                                    outp, st4, BATCH, 392, 784);
    // final: sigmoid(bn(z4)) in place
    bn_sigmoid_inplace<<<256, 256, 0, stream>>>(outp, st4, g4, b4, 784);
}

// Round 6
// 83.139 us; speedup vs baseline: 3.8486x; 1.0673x over previous
//
#include <hip/hip_runtime.h>
#include <hip/hip_bf16.h>
#include <math.h>

#define BATCH 1024
#define BM 32
#define BN 64
#define BK 64
#define LDK 72   // bf16 units; 144B row stride -> 16B-aligned frags, 2-way read conflicts (free)
#define NRB 32   // row-blocks = BATCH/BM

typedef __attribute__((ext_vector_type(8))) short bf16x8;
typedef __attribute__((ext_vector_type(8))) ushort ushort8;
typedef __attribute__((ext_vector_type(4))) float f32x4;

static __device__ __forceinline__ ushort f2bf(float f) {
    union { float f; unsigned u; } v; v.f = f;
    unsigned r = (v.u + 0x7fffu + ((v.u >> 16) & 1u)) >> 16;  // RNE
    return (ushort)r;
}

// ============ fused GEMM: [consumer-side BN+ReLU on A] + euclid + column-stat partials ============
// A_eff[r][k] = NORM ? relu(A[r][k]*scale_k + shift_k) : A[r][k]
// Z[r][c] = A_eff[r]·B[:,c] - 0.5*(||A_eff[r]||^2 + ||B[:,c]||^2)   (dot bf16 MFMA, rest fp32)
// stats_out[rowblock][c] = (sum_r z, sum_r z^2) over this block's BM rows.
template <int NORM>
__global__ __launch_bounds__(256) void gemm_fused(
    const float* __restrict__ A, const float* __restrict__ Bw,
    const float2* __restrict__ stats_in, const float* __restrict__ gamma, const float* __restrict__ beta,
    float* __restrict__ Z, float2* __restrict__ stats_out,
    int M, int K, int N)
{
    __shared__ ushort As[2][BM][LDK];
    __shared__ ushort Bs[2][BN][LDK];
    __shared__ float scaleK[784], shiftK[784];
    __shared__ float bred[4 * BN];
    __shared__ float xsq_s[BM], wsq_s[BN];
    __shared__ float cs[2][BN], cq[2][BN];

    const int tid = threadIdx.x;
    const int lane = tid & 63;
    const int wv = tid >> 6;
    const int wr = wv >> 1, wc = wv & 1;      // 2x2 waves: 16 rows x 32 cols each
    const int row0 = blockIdx.y * BM, col0 = blockIdx.x * BN;
    const int ar = tid >> 3;                  // 0..31 (A row)
    const int ak0 = (tid & 7) * 8;            // 0..56 (A k-chunk of 8)
    const int bn = tid & 63;                  // B col
    const int bk0 = (tid >> 6) * 16;          // B k-chunk of 16
    const int fr = lane & 15;
    const int fg = lane >> 4;

    // ---- finalize producer BN stats for the K input features ----
    if (NORM) {
        for (int k = tid; k < K; k += 256) {
            double s = 0.0, q = 0.0;
            #pragma unroll 4
            for (int rb = 0; rb < NRB; ++rb) {
                float2 p = stats_in[rb * K + k];
                s += (double)p.x; q += (double)p.y;
            }
            double mean = s * (1.0 / BATCH);
            double var = q * (1.0 / BATCH) - mean * mean;
            float inv = (float)(1.0 / sqrt(var + 1e-5));
            float sc = gamma[k] * inv;
            scaleK[k] = sc;
            shiftK[k] = beta[k] - (float)mean * sc;
        }
        __syncthreads();
    }

    f32x4 acc[2] = {};       // n = 0,1 (two 16-col frags)
    float asq = 0.f;
    float bsq = 0.f;
    float areg[8];
    float breg[16];
    const int ntiles = (K + BK - 1) / BK;

    auto load_tile = [&](int t) {
        const int kbase = t * BK;
        if (kbase + BK <= K) {
            const float* p = A + (size_t)(row0 + ar) * K + kbase + ak0;
            f32x4 v0 = *(const f32x4*)p;
            f32x4 v1 = *(const f32x4*)(p + 4);
            #pragma unroll
            for (int j = 0; j < 4; ++j) { areg[j] = v0[j]; areg[4 + j] = v1[j]; }
            if (NORM) {
                #pragma unroll
                for (int j = 0; j < 8; ++j)
                    areg[j] = fmaxf(areg[j] * scaleK[kbase + ak0 + j] + shiftK[kbase + ak0 + j], 0.f);
            }
            const int gc = col0 + bn;
            #pragma unroll
            for (int i = 0; i < 16; ++i)
                breg[i] = (gc < N) ? Bw[(size_t)(kbase + bk0 + i) * N + gc] : 0.f;
        } else {
            #pragma unroll
            for (int j = 0; j < 8; ++j) {
                int gk = kbase + ak0 + j;
                float x = 0.f;
                if (gk < K) {
                    x = A[(size_t)(row0 + ar) * K + gk];
                    if (NORM) x = fmaxf(x * scaleK[gk] + shiftK[gk], 0.f);
                }
                areg[j] = x;
            }
            const int gc = col0 + bn;
            #pragma unroll
            for (int i = 0; i < 16; ++i) {
                int gk = kbase + bk0 + i;
                breg[i] = (gk < K && gc < N) ? Bw[(size_t)gk * N + gc] : 0.f;
            }
        }
    };

    auto store_tile = [&](int buf) {
        ushort8 h;
        #pragma unroll
        for (int j = 0; j < 8; ++j) {
            h[j] = f2bf(areg[j]);
            asq += areg[j] * areg[j];
        }
        *(ushort8*)&As[buf][ar][ak0] = h;           // one 16B ds_write
        ushort8 e0, e1;
        #pragma unroll
        for (int i = 0; i < 8; ++i) {
            e0[i] = f2bf(breg[i]);      bsq += breg[i] * breg[i];
            e1[i] = f2bf(breg[8 + i]);  bsq += breg[8 + i] * breg[8 + i];
        }
        *(ushort8*)&Bs[buf][bn][bk0] = e0;          // 2 x 16B ds_write
        *(ushort8*)&Bs[buf][bn][bk0 + 8] = e1;
    };

    auto compute = [&](int buf) {
        bf16x8 af[2], bfr[2][2];
        #pragma unroll
        for (int kk = 0; kk < 2; ++kk)
            af[kk] = *(const bf16x8*)&As[buf][wr * 16 + fr][kk * 32 + fg * 8];
        #pragma unroll
        for (int n = 0; n < 2; ++n)
            #pragma unroll
            for (int kk = 0; kk < 2; ++kk)
                bfr[n][kk] = *(const bf16x8*)&Bs[buf][wc * 32 + n * 16 + fr][kk * 32 + fg * 8];
        #pragma unroll
        for (int n = 0; n < 2; ++n)
            #pragma unroll
            for (int kk = 0; kk < 2; ++kk)
                acc[n] = __builtin_amdgcn_mfma_f32_16x16x32_bf16(af[kk], bfr[n][kk], acc[n], 0, 0, 0);
    };

    load_tile(0);
    store_tile(0);
    __syncthreads();
    for (int t = 0; t < ntiles; ++t) {
        if (t + 1 < ntiles) load_tile(t + 1);
        compute(t & 1);
        if (t + 1 < ntiles) store_tile((t + 1) & 1);
        __syncthreads();
    }

    // ---- xsq: fold the 8 threads sharing row ar (consecutive lanes) ----
    {
        float s = asq;
        s += __shfl_xor(s, 1, 64);
        s += __shfl_xor(s, 2, 64);
        s += __shfl_xor(s, 4, 64);
        if ((tid & 7) == 0) xsq_s[ar] = s;
    }
    // ---- wsq: fold 4 k-chunks ----
    bred[(tid >> 6) * BN + bn] = bsq;
    __syncthreads();
    if (tid < BN) wsq_s[tid] = bred[0*BN+tid] + bred[1*BN+tid] + bred[2*BN+tid] + bred[3*BN+tid];
    __syncthreads();

    // ---- epilogue: euclid adjust, write Z, column-stat partials ----
    // C/D layout: col = fr, row = fg*4 + j  (verified rounds 3-5)
    #pragma unroll
    for (int n = 0; n < 2; ++n) {
        const int c64 = wc * 32 + n * 16 + fr;
        const int c = col0 + c64;
        const float wsq = wsq_s[c64];
        float ps = 0.f, pq = 0.f;
        #pragma unroll
        for (int j = 0; j < 4; ++j) {
            const int rl = wr * 16 + fg * 4 + j;
            float zv = acc[n][j] - 0.5f * (xsq_s[rl] + wsq);
            ps += zv; pq += zv * zv;
            if (c < N) Z[(size_t)(row0 + rl) * N + c] = zv;
        }
        ps += __shfl_xor(ps, 16, 64); ps += __shfl_xor(ps, 32, 64);
        pq += __shfl_xor(pq, 16, 64); pq += __shfl_xor(pq, 32, 64);
        if (fg == 0) { cs[wr][c64] = ps; cq[wr][c64] = pq; }
    }
    __syncthreads();
    if (tid < BN) {
        int c = col0 + tid;
        if (c < N)
            stats_out[blockIdx.y * N + c] = make_float2(cs[0][tid] + cs[1][tid],
                                                        cq[0][tid] + cq[1][tid]);
    }
}

// ============ final BN + sigmoid, in place on d_out ============
__global__ __launch_bounds__(256) void bn_sigmoid_inplace(
    float* __restrict__ Zout, const float2* __restrict__ stats,
    const float* __restrict__ gamma, const float* __restrict__ beta, int N)
{
    __shared__ float sc[784], sh[784];
    for (int k = threadIdx.x; k < N; k += 256) {
        double s = 0.0, q = 0.0;
        #pragma unroll 4
        for (int rb = 0; rb < NRB; ++rb) {
            float2 p = stats[rb * N + k];
            s += (double)p.x; q += (double)p.y;
        }
        double mean = s * (1.0 / BATCH);
        double var = q * (1.0 / BATCH) - mean * mean;
        float inv = (float)(1.0 / sqrt(var + 1e-5));
        float scv = gamma[k] * inv;
        sc[k] = scv;
        sh[k] = beta[k] - (float)mean * scv;
    }
    __syncthreads();
    const int nf4 = BATCH * N / 4;
    f32x4* p = (f32x4*)Zout;
    for (int i = blockIdx.x * 256 + threadIdx.x; i < nf4; i += gridDim.x * 256) {
        f32x4 v = p[i];
        int k = (i * 4) % N;
        #pragma unroll
        for (int j = 0; j < 4; ++j) {
            float y = v[j] * sc[k + j] + sh[k + j];
            v[j] = 1.f / (1.f + expf(-y));
        }
        p[i] = v;
    }
}

extern "C" void kernel_launch(void* const* d_in, const int* in_sizes, int n_in,
                              void* d_out, int out_size, void* d_ws, size_t ws_size,
                              hipStream_t stream) {
    const float* X  = (const float*)d_in[0];
    const float* W1 = (const float*)d_in[1];
    const float* g1 = (const float*)d_in[2];
    const float* b1 = (const float*)d_in[3];
    const float* W2 = (const float*)d_in[4];
    const float* g2 = (const float*)d_in[5];
    const float* b2 = (const float*)d_in[6];
    const float* W3 = (const float*)d_in[7];
    const float* g3 = (const float*)d_in[8];
    const float* b3 = (const float*)d_in[9];
    const float* W4 = (const float*)d_in[10];
    const float* g4 = (const float*)d_in[11];
    const float* b4 = (const float*)d_in[12];

    float* ws = (float*)d_ws;
    float*  z1  = ws;                       // 1024*392
    float*  z2  = z1 + 1024 * 392;          // 1024*8
    float*  z3  = z2 + 1024 * 8;            // 1024*392
    float2* st1 = (float2*)(z3 + 1024 * 392);       // [32][392]
    float2* st2 = st1 + NRB * 392;                  // [32][8]
    float2* st3 = st2 + NRB * 8;                    // [32][392]
    float2* st4 = st3 + NRB * 392;                  // [32][784]
    float* outp = (float*)d_out;

    // L1: X[1024,784] -> z1[1024,392]           (A raw)
    gemm_fused<0><<<dim3(7, NRB), 256, 0, stream>>>(X, W1, nullptr, nullptr, nullptr,
                                                    z1, st1, BATCH, 784, 392);
    // L2: relu(bn(z1)) @ W2 -> z2[1024,8]
    gemm_fused<1><<<dim3(1, NRB), 256, 0, stream>>>(z1, W2, st1, g1, b1,
                                                    z2, st2, BATCH, 392, 8);
    // L3: relu(bn(z2)) @ W3 -> z3[1024,392]
    gemm_fused<1><<<dim3(7, NRB), 256, 0, stream>>>(z2, W3, st2, g2, b2,
                                                    z3, st3, BATCH, 8, 392);
    // L4: relu(bn(z3)) @ W4 -> d_out (pre-BN z4)
    gemm_fused<1><<<dim3(13, NRB), 256, 0, stream>>>(z3, W4, st3, g3, b3,
                                                     outp, st4, BATCH, 392, 784);
    // final: sigmoid(bn(z4)) in place
    bn_sigmoid_inplace<<<256, 256, 0, stream>>>(outp, st4, g4, b4, 784);
}

// Round 7
// 82.538 us; speedup vs baseline: 3.8767x; 1.0073x over previous
//
#include <hip/hip_runtime.h>
#include <hip/hip_bf16.h>
#include <math.h>

#define BATCH 1024
#define BM 32
#define BN 64
#define BK 64
#define LDK 72   // bf16 units; 144B row stride -> 16B-aligned frags, 2-way read conflicts (free)
#define NRB 32   // row-blocks = BATCH/BM

typedef __attribute__((ext_vector_type(8))) short bf16x8;
typedef __attribute__((ext_vector_type(8))) ushort ushort8;
typedef __attribute__((ext_vector_type(4))) float f32x4;

static __device__ __forceinline__ ushort f2bf(float f) {
    union { float f; unsigned u; } v; v.f = f;
    unsigned r = (v.u + 0x7fffu + ((v.u >> 16) & 1u)) >> 16;  // RNE
    return (ushort)r;
}
static __device__ __forceinline__ float bf2f(ushort u) {
    union { unsigned u; float f; } v; v.u = ((unsigned)u) << 16;
    return v.f;
}

// ============ prep: W[K][N] fp32 -> Wt[N][K] bf16 (LDS-tiled transpose), all 4 layers ============
__global__ __launch_bounds__(256) void prep_weights(
    const float* __restrict__ W1, const float* __restrict__ W2,
    const float* __restrict__ W3, const float* __restrict__ W4,
    ushort* __restrict__ Wt1, ushort* __restrict__ Wt2,
    ushort* __restrict__ Wt3, ushort* __restrict__ Wt4)
{
    __shared__ float tile[64][65];
    const int bid = blockIdx.x, tid = threadIdx.x;

    const float* W; ushort* Wt; int K, N, kt, nt;
    if (bid < 91)       { W = W1; Wt = Wt1; K = 784; N = 392; kt = bid % 13;       nt = bid / 13; }
    else if (bid < 98)  { W = W2; Wt = Wt2; K = 392; N = 8;   kt = bid - 91;       nt = 0; }
    else if (bid < 105) { W = W3; Wt = Wt3; K = 8;   N = 392; kt = 0;              nt = bid - 98; }
    else                { int r = bid - 105; W = W4; Wt = Wt4; K = 392; N = 784;   kt = r % 7;    nt = r / 7; }

    const int k0 = kt * 64, n0 = nt * 64;
    // read: coalesced over n
    #pragma unroll
    for (int it = 0; it < 16; ++it) {
        int e = it * 256 + tid;
        int kk = e >> 6, nn = e & 63;
        int gk = k0 + kk, gn = n0 + nn;
        tile[kk][nn] = (gk < K && gn < N) ? W[(size_t)gk * N + gn] : 0.f;
    }
    __syncthreads();
    // write: coalesced over k (transposed), convert to bf16
    #pragma unroll
    for (int it = 0; it < 16; ++it) {
        int e = it * 256 + tid;
        int nn = e >> 6, kk = e & 63;
        int gk = k0 + kk, gn = n0 + nn;
        if (gk < K && gn < N) Wt[(size_t)gn * K + gk] = f2bf(tile[kk][nn]);
    }
}

// ============ fused GEMM: [consumer-side BN+ReLU on A] + euclid + column-stat partials ============
// A_eff[r][k] = NORM ? relu(A[r][k]*scale_k + shift_k) : A[r][k]
// Z[r][c] = A_eff[r]·B[:,c] - 0.5*(||A_eff[r]||^2 + ||B[:,c]||^2)   (dot bf16 MFMA, rest fp32)
// B comes pre-transposed pre-converted: Wt[N][K] bf16. wsq from bf16 values — output-invariant,
// since a per-column wsq offset is removed exactly by BN's per-column mean subtraction.
// stats_out[rowblock][c] = (sum_r z, sum_r z^2) over this block's BM rows.
template <int NORM>
__global__ __launch_bounds__(256) void gemm_fused(
    const float* __restrict__ A, const ushort* __restrict__ Wt,
    const float2* __restrict__ stats_in, const float* __restrict__ gamma, const float* __restrict__ beta,
    float* __restrict__ Z, float2* __restrict__ stats_out,
    int M, int K, int N)
{
    __shared__ ushort As[2][BM][LDK];
    __shared__ ushort Bs[2][BN][LDK];
    __shared__ float scaleK[784], shiftK[784];
    __shared__ float bred[4 * BN];
    __shared__ float xsq_s[BM], wsq_s[BN];
    __shared__ float cs[2][BN], cq[2][BN];

    const int tid = threadIdx.x;
    const int lane = tid & 63;
    const int wv = tid >> 6;
    const int wr = wv >> 1, wc = wv & 1;      // 2x2 waves: 16 rows x 32 cols each
    const int row0 = blockIdx.y * BM, col0 = blockIdx.x * BN;
    const int ar = tid >> 3;                  // 0..31 (A row)
    const int ak0 = (tid & 7) * 8;            // 0..56 (A k-chunk of 8)
    const int bn = tid & 63;                  // B col
    const int bk0 = (tid >> 6) * 16;          // B k-chunk of 16
    const int fr = lane & 15;
    const int fg = lane >> 4;

    // ---- finalize producer BN stats for the K input features ----
    if (NORM) {
        for (int k = tid; k < K; k += 256) {
            double s = 0.0, q = 0.0;
            #pragma unroll 4
            for (int rb = 0; rb < NRB; ++rb) {
                float2 p = stats_in[rb * K + k];
                s += (double)p.x; q += (double)p.y;
            }
            double mean = s * (1.0 / BATCH);
            double var = q * (1.0 / BATCH) - mean * mean;
            float inv = (float)(1.0 / sqrt(var + 1e-5));
            float sc = gamma[k] * inv;
            scaleK[k] = sc;
            shiftK[k] = beta[k] - (float)mean * sc;
        }
        __syncthreads();
    }

    f32x4 acc[2] = {};       // n = 0,1 (two 16-col frags)
    float asq = 0.f;
    float bsq = 0.f;
    float areg[8];
    ushort8 bh[2];
    const int ntiles = (K + BK - 1) / BK;

    auto load_tile = [&](int t) {
        const int kbase = t * BK;
        const int gc = col0 + bn;
        if (kbase + BK <= K) {
            const float* p = A + (size_t)(row0 + ar) * K + kbase + ak0;
            f32x4 v0 = *(const f32x4*)p;
            f32x4 v1 = *(const f32x4*)(p + 4);
            #pragma unroll
            for (int j = 0; j < 4; ++j) { areg[j] = v0[j]; areg[4 + j] = v1[j]; }
            if (NORM) {
                #pragma unroll
                for (int j = 0; j < 8; ++j)
                    areg[j] = fmaxf(areg[j] * scaleK[kbase + ak0 + j] + shiftK[kbase + ak0 + j], 0.f);
            }
            if (gc < N) {
                const ushort* q = Wt + (size_t)gc * K + kbase + bk0;
                bh[0] = *(const ushort8*)q;
                bh[1] = *(const ushort8*)(q + 8);
            } else {
                bh[0] = (ushort8)0; bh[1] = (ushort8)0;
            }
        } else {
            #pragma unroll
            for (int j = 0; j < 8; ++j) {
                int gk = kbase + ak0 + j;
                float x = 0.f;
                if (gk < K) {
                    x = A[(size_t)(row0 + ar) * K + gk];
                    if (NORM) x = fmaxf(x * scaleK[gk] + shiftK[gk], 0.f);
                }
                areg[j] = x;
            }
            #pragma unroll
            for (int i = 0; i < 16; ++i) {
                int gk = kbase + bk0 + i;
                ushort u = (gk < K && gc < N) ? Wt[(size_t)gc * K + gk] : (ushort)0;
                bh[i >> 3][i & 7] = u;
            }
        }
    };

    auto store_tile = [&](int buf) {
        ushort8 h;
        #pragma unroll
        for (int j = 0; j < 8; ++j) {
            h[j] = f2bf(areg[j]);
            asq += areg[j] * areg[j];
        }
        *(ushort8*)&As[buf][ar][ak0] = h;           // one 16B ds_write
        #pragma unroll
        for (int i = 0; i < 8; ++i) {
            float f0 = bf2f(bh[0][i]); bsq += f0 * f0;
            float f1 = bf2f(bh[1][i]); bsq += f1 * f1;
        }
        *(ushort8*)&Bs[buf][bn][bk0] = bh[0];       // 2 x 16B ds_write
        *(ushort8*)&Bs[buf][bn][bk0 + 8] = bh[1];
    };

    auto compute = [&](int buf) {
        bf16x8 af[2], bfr[2][2];
        #pragma unroll
        for (int kk = 0; kk < 2; ++kk)
            af[kk] = *(const bf16x8*)&As[buf][wr * 16 + fr][kk * 32 + fg * 8];
        #pragma unroll
        for (int n = 0; n < 2; ++n)
            #pragma unroll
            for (int kk = 0; kk < 2; ++kk)
                bfr[n][kk] = *(const bf16x8*)&Bs[buf][wc * 32 + n * 16 + fr][kk * 32 + fg * 8];
        #pragma unroll
        for (int n = 0; n < 2; ++n)
            #pragma unroll
            for (int kk = 0; kk < 2; ++kk)
                acc[n] = __builtin_amdgcn_mfma_f32_16x16x32_bf16(af[kk], bfr[n][kk], acc[n], 0, 0, 0);
    };

    load_tile(0);
    store_tile(0);
    __syncthreads();
    for (int t = 0; t < ntiles; ++t) {
        if (t + 1 < ntiles) load_tile(t + 1);
        compute(t & 1);
        if (t + 1 < ntiles) store_tile((t + 1) & 1);
        __syncthreads();
    }

    // ---- xsq: fold the 8 threads sharing row ar ----
    {
        float s = asq;
        s += __shfl_xor(s, 1, 64);
        s += __shfl_xor(s, 2, 64);
        s += __shfl_xor(s, 4, 64);
        if ((tid & 7) == 0) xsq_s[ar] = s;
    }
    // ---- wsq: fold 4 k-chunks ----
    bred[(tid >> 6) * BN + bn] = bsq;
    __syncthreads();
    if (tid < BN) wsq_s[tid] = bred[0*BN+tid] + bred[1*BN+tid] + bred[2*BN+tid] + bred[3*BN+tid];
    __syncthreads();

    // ---- epilogue: euclid adjust, write Z, column-stat partials ----
    // C/D layout: col = fr, row = fg*4 + j  (verified rounds 3-6)
    #pragma unroll
    for (int n = 0; n < 2; ++n) {
        const int c64 = wc * 32 + n * 16 + fr;
        const int c = col0 + c64;
        const float wsq = wsq_s[c64];
        float ps = 0.f, pq = 0.f;
        #pragma unroll
        for (int j = 0; j < 4; ++j) {
            const int rl = wr * 16 + fg * 4 + j;
            float zv = acc[n][j] - 0.5f * (xsq_s[rl] + wsq);
            ps += zv; pq += zv * zv;
            if (c < N) Z[(size_t)(row0 + rl) * N + c] = zv;
        }
        ps += __shfl_xor(ps, 16, 64); ps += __shfl_xor(ps, 32, 64);
        pq += __shfl_xor(pq, 16, 64); pq += __shfl_xor(pq, 32, 64);
        if (fg == 0) { cs[wr][c64] = ps; cq[wr][c64] = pq; }
    }
    __syncthreads();
    if (tid < BN) {
        int c = col0 + tid;
        if (c < N)
            stats_out[blockIdx.y * N + c] = make_float2(cs[0][tid] + cs[1][tid],
                                                        cq[0][tid] + cq[1][tid]);
    }
}

// ============ final BN + sigmoid, in place on d_out ============
__global__ __launch_bounds__(256) void bn_sigmoid_inplace(
    float* __restrict__ Zout, const float2* __restrict__ stats,
    const float* __restrict__ gamma, const float* __restrict__ beta, int N)
{
    __shared__ float sc[784], sh[784];
    for (int k = threadIdx.x; k < N; k += 256) {
        double s = 0.0, q = 0.0;
        #pragma unroll 4
        for (int rb = 0; rb < NRB; ++rb) {
            float2 p = stats[rb * N + k];
            s += (double)p.x; q += (double)p.y;
        }
        double mean = s * (1.0 / BATCH);
        double var = q * (1.0 / BATCH) - mean * mean;
        float inv = (float)(1.0 / sqrt(var + 1e-5));
        float scv = gamma[k] * inv;
        sc[k] = scv;
        sh[k] = beta[k] - (float)mean * scv;
    }
    __syncthreads();
    const int nf4 = BATCH * N / 4;
    f32x4* p = (f32x4*)Zout;
    for (int i = blockIdx.x * 256 + threadIdx.x; i < nf4; i += gridDim.x * 256) {
        f32x4 v = p[i];
        int k = (i * 4) % N;
        #pragma unroll
        for (int j = 0; j < 4; ++j) {
            float y = v[j] * sc[k + j] + sh[k + j];
            v[j] = 1.f / (1.f + expf(-y));
        }
        p[i] = v;
    }
}

extern "C" void kernel_launch(void* const* d_in, const int* in_sizes, int n_in,
                              void* d_out, int out_size, void* d_ws, size_t ws_size,
                              hipStream_t stream) {
    const float* X  = (const float*)d_in[0];
    const float* W1 = (const float*)d_in[1];
    const float* g1 = (const float*)d_in[2];
    const float* b1 = (const float*)d_in[3];
    const float* W2 = (const float*)d_in[4];
    const float* g2 = (const float*)d_in[5];
    const float* b2 = (const float*)d_in[6];
    const float* W3 = (const float*)d_in[7];
    const float* g3 = (const float*)d_in[8];
    const float* b3 = (const float*)d_in[9];
    const float* W4 = (const float*)d_in[10];
    const float* g4 = (const float*)d_in[11];
    const float* b4 = (const float*)d_in[12];

    float* ws = (float*)d_ws;
    float*  z1  = ws;                       // 1024*392
    float*  z2  = z1 + 1024 * 392;          // 1024*8
    float*  z3  = z2 + 1024 * 8;            // 1024*392
    float2* st1 = (float2*)(z3 + 1024 * 392);       // [32][392]
    float2* st2 = st1 + NRB * 392;                  // [32][8]
    float2* st3 = st2 + NRB * 8;                    // [32][392]
    float2* st4 = st3 + NRB * 392;                  // [32][784]
    ushort* Wt1 = (ushort*)(st4 + NRB * 784);       // [392][784]
    ushort* Wt2 = Wt1 + 392 * 784;                  // [8][392]
    ushort* Wt3 = Wt2 + 8 * 392;                    // [392][8]
    ushort* Wt4 = Wt3 + 392 * 8;                    // [784][392]
    float* outp = (float*)d_out;

    // prep: transpose+convert all weights to bf16 [N][K]
    prep_weights<<<196, 256, 0, stream>>>(W1, W2, W3, W4, Wt1, Wt2, Wt3, Wt4);

    // L1: X[1024,784] -> z1[1024,392]           (A raw)
    gemm_fused<0><<<dim3(7, NRB), 256, 0, stream>>>(X, Wt1, nullptr, nullptr, nullptr,
                                                    z1, st1, BATCH, 784, 392);
    // L2: relu(bn(z1)) @ W2 -> z2[1024,8]
    gemm_fused<1><<<dim3(1, NRB), 256, 0, stream>>>(z1, Wt2, st1, g1, b1,
                                                    z2, st2, BATCH, 392, 8);
    // L3: relu(bn(z2)) @ W3 -> z3[1024,392]
    gemm_fused<1><<<dim3(7, NRB), 256, 0, stream>>>(z2, Wt3, st2, g2, b2,
                                                    z3, st3, BATCH, 8, 392);
    // L4: relu(bn(z3)) @ W4 -> d_out (pre-BN z4)
    gemm_fused<1><<<dim3(13, NRB), 256, 0, stream>>>(z3, Wt4, st3, g3, b3,
                                                     outp, st4, BATCH, 392, 784);
    // final: sigmoid(bn(z4)) in place
    bn_sigmoid_inplace<<<256, 256, 0, stream>>>(outp, st4, g4, b4, 784);
}